// Round 1
// baseline (158.394 us; speedup 1.0000x reference)
//
#include <hip/hip_runtime.h>
#include <hip/hip_bf16.h>

#define DDIM 2048
#define TTIMES 256
#define BM 128
#define BN 256
#define BK 32
#define NT (DDIM / BK)      // 64 K-steps
#define THREADS 512
#define LDSW 40             // ushorts per LDS row: 32 data + 8 pad = 80 B stride

typedef __attribute__((ext_vector_type(8))) short short8;
typedef __attribute__((ext_vector_type(4))) float f32x4;

__device__ __forceinline__ ushort f2bf(float f) {
    union { float f; unsigned int u; } v; v.f = f;
    unsigned int u = v.u;
    unsigned int r = (u + 0x7FFFu + ((u >> 16) & 1u)) >> 16;   // RNE
    return (ushort)r;
}
__device__ __forceinline__ float bf2f(ushort u) {
    union { unsigned int u; float f; } v; v.u = ((unsigned int)u) << 16;
    return v.f;
}

// ---------------- normalize org rows -> bf16 o in workspace ----------------
__global__ void norm_rows(const float* __restrict__ org, ushort* __restrict__ obf) {
    const int a   = blockIdx.x;     // time row
    const int tid = threadIdx.x;    // 256 threads
    const float* row = org + (size_t)a * DDIM;
    float4 v0 = ((const float4*)row)[tid * 2];
    float4 v1 = ((const float4*)row)[tid * 2 + 1];
    float s = v0.x*v0.x + v0.y*v0.y + v0.z*v0.z + v0.w*v0.w
            + v1.x*v1.x + v1.y*v1.y + v1.z*v1.z + v1.w*v1.w;
    #pragma unroll
    for (int off = 1; off < 64; off <<= 1) s += __shfl_xor(s, off);
    __shared__ float wsum[4];
    const int lane = tid & 63, w = tid >> 6;
    if (lane == 0) wsum[w] = s;
    __syncthreads();
    const float tot = wsum[0] + wsum[1] + wsum[2] + wsum[3];
    const float scale = 1.0f / fmaxf(sqrtf(tot), 1e-12f);
    union { ushort u[8]; uint4 v; } pk;
    pk.u[0] = f2bf(v0.x * scale); pk.u[1] = f2bf(v0.y * scale);
    pk.u[2] = f2bf(v0.z * scale); pk.u[3] = f2bf(v0.w * scale);
    pk.u[4] = f2bf(v1.x * scale); pk.u[5] = f2bf(v1.y * scale);
    pk.u[6] = f2bf(v1.z * scale); pk.u[7] = f2bf(v1.w * scale);
    ((uint4*)(obf + (size_t)a * DDIM))[tid] = pk.v;
}

// ---------------- fused GEMM + weighted trace reduce ----------------
__global__ __launch_bounds__(THREADS, 4) void gemm_trace(
    const float* __restrict__ x, const ushort* __restrict__ obf,
    float* __restrict__ part)
{
    __shared__ __align__(16) ushort Ab[2][BM * LDSW];   // 20480 B
    __shared__ __align__(16) ushort Bb[2][BN * LDSW];   // 40960 B

    const int tid  = threadIdx.x;
    const int lane = tid & 63;
    const int wid  = tid >> 6;     // 0..7
    const int wm   = wid >> 2;     // 0..1  (M)
    const int wn   = wid & 3;      // 0..3  (N)
    const int rb   = blockIdx.x;   // 0..15 row-block
    const int d    = blockIdx.y;   // 0..31 batch

    const float* xtile = x + (size_t)d * DDIM * DDIM + (size_t)(rb * BM) * DDIM;

    // A staging: 1024 float4 chunks (128 rows x 8 chunks); 2 per thread
    const int ar0 = tid >> 3,         akq = tid & 7;   // rows 0..63
    const int ar1 = (tid + 512) >> 3;                  // rows 64..127
    // B staging: 1024 16B chunks (256 rows x 4 chunks); 2 per thread
    const int br0 = tid >> 2,         bkq = tid & 3;   // rows 0..127
    const int br1 = (tid + 512) >> 2;                  // rows 128..255

    float4 a0 = *(const float4*)(xtile + (size_t)ar0 * DDIM + akq * 4);
    float4 a1 = *(const float4*)(xtile + (size_t)ar1 * DDIM + akq * 4);
    uint4  b0 = *(const uint4*)(obf + (size_t)br0 * DDIM + bkq * 8);
    uint4  b1 = *(const uint4*)(obf + (size_t)br1 * DDIM + bkq * 8);

    f32x4 acc[4][4];
    #pragma unroll
    for (int mi = 0; mi < 4; ++mi)
        #pragma unroll
        for (int ni = 0; ni < 4; ++ni)
            acc[mi][ni] = (f32x4){0.f, 0.f, 0.f, 0.f};

    const int lrow = lane & 15;
    const int koff = (lane >> 4) * 8;   // ushort units within row

    for (int t = 0; t < NT; ++t) {
        const int buf = t & 1;
        // ---- write staged regs to LDS ----
        {
            union { ushort u[4]; uint2 v; } p;
            p.u[0] = f2bf(a0.x); p.u[1] = f2bf(a0.y); p.u[2] = f2bf(a0.z); p.u[3] = f2bf(a0.w);
            *(uint2*)&Ab[buf][ar0 * LDSW + akq * 4] = p.v;
            p.u[0] = f2bf(a1.x); p.u[1] = f2bf(a1.y); p.u[2] = f2bf(a1.z); p.u[3] = f2bf(a1.w);
            *(uint2*)&Ab[buf][ar1 * LDSW + akq * 4] = p.v;
        }
        *(uint4*)&Bb[buf][br0 * LDSW + bkq * 8] = b0;
        *(uint4*)&Bb[buf][br1 * LDSW + bkq * 8] = b1;
        __syncthreads();
        // ---- issue next-tile global loads (fly under compute) ----
        if (t + 1 < NT) {
            const float*  xk = xtile + (t + 1) * BK;
            const ushort* ok = obf   + (t + 1) * BK;
            a0 = *(const float4*)(xk + (size_t)ar0 * DDIM + akq * 4);
            a1 = *(const float4*)(xk + (size_t)ar1 * DDIM + akq * 4);
            b0 = *(const uint4*)(ok + (size_t)br0 * DDIM + bkq * 8);
            b1 = *(const uint4*)(ok + (size_t)br1 * DDIM + bkq * 8);
        }
        // ---- compute ----
        short8 af[4], bfr[4];
        #pragma unroll
        for (int mi = 0; mi < 4; ++mi)
            af[mi] = *(const short8*)&Ab[buf][(wm * 64 + mi * 16 + lrow) * LDSW + koff];
        #pragma unroll
        for (int ni = 0; ni < 4; ++ni)
            bfr[ni] = *(const short8*)&Bb[buf][(wn * 64 + ni * 16 + lrow) * LDSW + koff];
        #pragma unroll
        for (int mi = 0; mi < 4; ++mi)
            #pragma unroll
            for (int ni = 0; ni < 4; ++ni)
                acc[mi][ni] = __builtin_amdgcn_mfma_f32_16x16x32_bf16(
                    af[mi], bfr[ni], acc[mi][ni], 0, 0, 0);
    }

    __syncthreads();   // done with tile LDS; overlay partial buffer
    float* plds = (float*)&Ab[0][0];   // 2 x 256 floats

    #pragma unroll
    for (int ni = 0; ni < 4; ++ni) {
        const int a_idx = wn * 64 + ni * 16 + lrow;    // time (col) index
        float ps = 0.f;
        #pragma unroll
        for (int mi = 0; mi < 4; ++mi) {
            // rows of this acc frag: m = wm*64 + mi*16 + (lane>>4)*4 + j
            const int bg = rb * BM + wm * 64 + mi * 16 + (lane >> 4) * 4;
            const ushort4 w = *(const ushort4*)(obf + (size_t)a_idx * DDIM + bg);
            ps += bf2f(w.x) * acc[mi][ni][0];
            ps += bf2f(w.y) * acc[mi][ni][1];
            ps += bf2f(w.z) * acc[mi][ni][2];
            ps += bf2f(w.w) * acc[mi][ni][3];
        }
        ps += __shfl_xor(ps, 16);
        ps += __shfl_xor(ps, 32);
        if (lane < 16) plds[wm * 256 + a_idx] = ps;
    }
    __syncthreads();
    if (tid < 256) {
        const float v = plds[tid] + plds[256 + tid];
        part[((size_t)(d * 16) + rb) * 256 + tid] = v;
    }
}

// ---------------- final reduce over row-blocks ----------------
__global__ void reduce_part(const float* __restrict__ part, float* __restrict__ out) {
    const int d = blockIdx.x;    // 32
    const int a = threadIdx.x;   // 256
    float s = 0.f;
    #pragma unroll
    for (int rb = 0; rb < 16; ++rb)
        s += part[((size_t)(d * 16) + rb) * 256 + a];
    out[(size_t)d * 256 + a] = s;
}

extern "C" void kernel_launch(void* const* d_in, const int* in_sizes, int n_in,
                              void* d_out, int out_size, void* d_ws, size_t ws_size,
                              hipStream_t stream) {
    const float* x   = (const float*)d_in[0];   // (32, 2048, 2048) fp32
    const float* org = (const float*)d_in[1];   // (256, 2048) fp32
    float* out = (float*)d_out;                 // (32, 256) fp32

    ushort* obf = (ushort*)d_ws;                          // 1 MiB: bf16 normalized o
    float*  prt = (float*)((char*)d_ws + (1 << 20));      // 512 KiB: partials

    norm_rows<<<dim3(TTIMES), dim3(256), 0, stream>>>(org, obf);
    gemm_trace<<<dim3(DDIM / BM, 32), dim3(THREADS), 0, stream>>>(x, obf, prt);
    reduce_part<<<dim3(32), dim3(256), 0, stream>>>(prt, out);
}